// Round 5
// baseline (294.189 us; speedup 1.0000x reference)
//
#include <hip/hip_runtime.h>

// ContrastiveLoss: normalize -> 256x256 bf16 MFMA GEMM (A @ B^T), ni-major
// 4-phase schedule with A-fragments register-resident per K-tile, fused
// mask/row-reduce epilogue -> final scalar reduce.
// N=8192, D=1024. Output: single f32 scalar.

constexpr int N = 8192;
constexpr int D = 1024;
constexpr int NT = D / 64;  // 16 K-tiles of BK=64

typedef short bf16x8 __attribute__((ext_vector_type(8)));
typedef float f32x4 __attribute__((ext_vector_type(4)));

static __device__ inline unsigned short f2bf(float f) {
  unsigned int u = __float_as_uint(f);
  unsigned int r = (u + 0x7fffu + ((u >> 16) & 1u)) >> 16;
  return (unsigned short)r;
}

// ---------------- normalize: fp32 row -> L2-normalized bf16 row -------------
__global__ __launch_bounds__(256) void normalize_kernel(
    const float* __restrict__ in_col, const float* __restrict__ in_row,
    unsigned short* __restrict__ out_col, unsigned short* __restrict__ out_row) {
  int r = blockIdx.x * 4 + (threadIdx.x >> 6);
  int lane = threadIdx.x & 63;
  const float* in =
      (r < N) ? in_col + (size_t)r * D : in_row + (size_t)(r - N) * D;
  unsigned short* out =
      (r < N) ? out_col + (size_t)r * D : out_row + (size_t)(r - N) * D;
  float4 v[4];
  float s = 0.f;
#pragma unroll
  for (int c = 0; c < 4; c++) {
    v[c] = ((const float4*)in)[lane + c * 64];
    s += v[c].x * v[c].x + v[c].y * v[c].y + v[c].z * v[c].z + v[c].w * v[c].w;
  }
#pragma unroll
  for (int off = 32; off >= 1; off >>= 1) s += __shfl_xor(s, off, 64);
  float inv = 1.0f / sqrtf(s + 1e-12f);
#pragma unroll
  for (int c = 0; c < 4; c++) {
    ushort4 o;
    o.x = f2bf(v[c].x * inv);
    o.y = f2bf(v[c].y * inv);
    o.z = f2bf(v[c].z * inv);
    o.w = f2bf(v[c].w * inv);
    ((ushort4*)out)[lane + c * 64] = o;
  }
}

// ---------------- fused GEMM + loss epilogue --------------------------------
// 512 thr = 8 waves (2 wave-rows x 4 wave-cols). Tile 256x256, BK=64.
// LDS: A [2dbuf][2half][128r][64k] + B same = 128 KiB, T2 XOR-swizzled.
// ni-major phases: P(ni+1) computes acc[0..7][ni]. A-frags (af[8][2], 64 VGPR)
// read once at P1. Stages: P1 B1(T+1), P2 A0(T+2), P3 A1(T+2)+B0(T+2),
// P4 vmcnt(6) drain (completes exactly tile-T+1's 4 halves; distances 3-6).
__global__ __launch_bounds__(512, 2) void loss_kernel(
    const unsigned short* __restrict__ An, const unsigned short* __restrict__ Bn,
    const int* __restrict__ tc, const int* __restrict__ tr,
    float* __restrict__ lossG, int* __restrict__ hasG) {
  __shared__ unsigned short lds[65536];  // A elems [0,32768), B [32768,65536)

  const int tid = threadIdx.x;
  const int lane = tid & 63;
  const int wid = tid >> 6;
  const int wr = wid >> 2;  // 0..1 (owns 128 rows)
  const int wc = wid & 3;   // 0..3 (owns 64 cols)

  // XCD-aware 2D swizzle: per-XCD resident-32 = 8i x 4j patch (B L2-pinned)
  const int bid = blockIdx.x;
  const int x = bid & 7, s = bid >> 3;
  const int iBase = (((s & 7) | ((s >> 5) << 3))) * 256;
  const int jBase = (x * 4 + ((s >> 3) & 3)) * 256;

  // fragment addressing (reads are T2-swizzled)
  const int frow = lane & 15;
  const int fkb = (lane >> 4) * 16;   // K byte offset within 64B k-chunk
  const int rxor = (lane & 7) << 4;   // T2 swizzle mask
  const int kx0 = (0 + fkb) ^ rxor;   // kk=0
  const int kx1 = (64 + fkb) ^ rxor;  // kk=1
  int rowA[4], rowB[2];
#pragma unroll
  for (int m2 = 0; m2 < 4; m2++) rowA[m2] = (wr * 64 + m2 * 16 + frow) * 128;
#pragma unroll
  for (int n2 = 0; n2 < 2; n2++) rowB[n2] = (wc * 32 + n2 * 16 + frow) * 128;

  // staging addressing
  const int rl0 = tid >> 3;                // 0..63
  const int kel = (tid & 7) * 8;           // element k within BK
  const int kSw = kel ^ ((rl0 & 7) << 3);  // inverse-swizzled source k
  const int rA0 = iBase + rl0;
  const int rB0 = jBase + ((rl0 >> 5) * 64) + (rl0 & 31);

#define GLDS(g, l)                                                        \
  __builtin_amdgcn_global_load_lds(                                       \
      (const __attribute__((address_space(1))) void*)(g),                 \
      (__attribute__((address_space(3))) void*)(l), 16, 0, 0)

  // stage half-tile of K-tile tt into dbuf parity P; tail wraps (tt&15) so
  // vmcnt counting stays uniform
#define STAGE_A(h, tt, P)                                                     \
  do {                                                                        \
    const int _k = ((tt) & 15) * 64 + kSw;                                    \
    unsigned short* _d = lds + (((P) * 2 + (h)) * 8192) + wid * 512;          \
    GLDS(An + (size_t)(rA0 + (h) * 64) * D + _k, _d);                         \
    GLDS(An + (size_t)(rA0 + 128 + (h) * 64) * D + _k, _d + 4096);            \
  } while (0)
#define STAGE_B(h, tt, P)                                                     \
  do {                                                                        \
    const int _k = ((tt) & 15) * 64 + kSw;                                    \
    unsigned short* _d = lds + 32768 + (((P) * 2 + (h)) * 8192) + wid * 512;  \
    GLDS(Bn + (size_t)(rB0 + (h) * 32) * D + _k, _d);                         \
    GLDS(Bn + (size_t)(rB0 + 128 + (h) * 32) * D + _k, _d + 4096);            \
  } while (0)
#define STAGE_A1B0(tt, P) \
  do { STAGE_A(1, tt, P); STAGE_B(0, tt, P); } while (0)
#define STAGE_NONE do {} while (0)

  f32x4 acc[8][4];
#pragma unroll
  for (int mi = 0; mi < 8; mi++)
#pragma unroll
    for (int ni = 0; ni < 4; ni++) acc[mi][ni] = (f32x4){0.f, 0.f, 0.f, 0.f};

  bf16x8 af[8][2], bf[2];
  const char* ldsc = (const char*)lds;

  // prologue: tile0 all 4 halves (8 loads) + A0,A1,B0 of tile1 (6 loads);
  // vmcnt(6) completes tile0, leaves the steady-state carry of 6.
  STAGE_A(0, 0, 0);
  STAGE_A(1, 0, 0);
  STAGE_B(0, 0, 0);
  STAGE_B(1, 0, 0);
  STAGE_A(0, 1, 1);
  STAGE_A(1, 1, 1);
  STAGE_B(0, 1, 1);
  asm volatile("s_waitcnt vmcnt(6)" ::: "memory");
  __builtin_amdgcn_s_barrier();
  asm volatile("" ::: "memory");

  // Phase: {bf reads (+af at P1), stage, [vmcnt(6) at P4], BAR, prio1,
  // MFMA ni, prio0}. Compiler emits counted lgkmcnt between reads and MFMAs.
#define PH(NI, LOADAF, DA, DB, STG, DRN)                                        \
  do {                                                                          \
    bf[0] = *(const bf16x8*)(ldsc + (DB) + ((NI) >> 1) * 16384 +                \
                             rowB[(NI) & 1] + kx0);                             \
    bf[1] = *(const bf16x8*)(ldsc + (DB) + ((NI) >> 1) * 16384 +                \
                             rowB[(NI) & 1] + kx1);                             \
    if (LOADAF) {                                                               \
      _Pragma("unroll") for (int mh = 0; mh < 2; mh++)                          \
          _Pragma("unroll") for (int m2 = 0; m2 < 4; m2++) {                    \
        af[mh * 4 + m2][0] =                                                    \
            *(const bf16x8*)(ldsc + (DA) + mh * 16384 + rowA[m2] + kx0);        \
        af[mh * 4 + m2][1] =                                                    \
            *(const bf16x8*)(ldsc + (DA) + mh * 16384 + rowA[m2] + kx1);        \
      }                                                                         \
    }                                                                           \
    STG;                                                                        \
    if (DRN) asm volatile("s_waitcnt vmcnt(6)" ::: "memory");                   \
    asm volatile("" ::: "memory");                                              \
    __builtin_amdgcn_s_barrier();                                               \
    asm volatile("" ::: "memory");                                              \
    __builtin_amdgcn_s_setprio(1);                                              \
    _Pragma("unroll") for (int kk = 0; kk < 2; kk++)                            \
        _Pragma("unroll") for (int m = 0; m < 8; m++)                           \
            acc[m][NI] = __builtin_amdgcn_mfma_f32_16x16x32_bf16(               \
                af[m][kk], bf[kk], acc[m][NI], 0, 0, 0);                        \
    __builtin_amdgcn_s_setprio(0);                                              \
  } while (0)

  // Tile T (parity P): B1(T+1)->B[1-P] (dead since T-1 P4); A(T+2)->A[P]
  // (dead since T P1); B0(T+2)->B[P] (dead since T P2). All >=1 barrier after
  // last read-issue + DMA latency.
#define TILE(T, P)                                                              \
  do {                                                                          \
    PH(0, true, (P) * 32768, 65536 + (P) * 32768,                               \
       STAGE_B(1, (T) + 1, 1 - (P)), 0);                                        \
    PH(1, false, (P) * 32768, 65536 + (P) * 32768,                              \
       STAGE_A(0, (T) + 2, (P)), 0);                                            \
    PH(2, false, (P) * 32768, 65536 + (P) * 32768,                              \
       STAGE_A1B0((T) + 2, (P)), 0);                                            \
    PH(3, false, (P) * 32768, 65536 + (P) * 32768, STAGE_NONE, 1);              \
  } while (0)

  for (int tp = 0; tp < NT / 2; ++tp) {
    const int t0 = 2 * tp;
    TILE(t0, 0);
    TILE(t0 + 1, 1);
  }
  asm volatile("s_waitcnt vmcnt(0)" ::: "memory");
#undef TILE
#undef PH
#undef STAGE_A1B0
#undef STAGE_NONE
#undef STAGE_A
#undef STAGE_B
#undef GLDS

  // ---- epilogue: mask + per-row reduce + sparse atomics ----
  // C/D layout: col = lane&15, row = (lane>>4)*4 + reg
  int trj[4];
#pragma unroll
  for (int ni = 0; ni < 4; ni++) trj[ni] = tr[jBase + wc * 64 + ni * 16 + frow];

#pragma unroll
  for (int mi = 0; mi < 8; mi++) {
#pragma unroll
    for (int r = 0; r < 4; r++) {
      const int i = iBase + wr * 128 + mi * 16 + (lane >> 4) * 4 + r;
      const int tci = tc[i];
      float v = 0.f;
      bool hasp = false;
#pragma unroll
      for (int ni = 0; ni < 4; ni++) {
        float s2 = acc[mi][ni][r];
        if (tci == trj[ni]) {
          if (s2 < 1.0f - 1e-5f) { v += 1.0f - s2; hasp = true; }
        } else if (s2 > 0.5f) {
          v += s2;
        }
      }
#pragma unroll
      for (int off = 1; off < 16; off <<= 1) v += __shfl_xor(v, off, 16);
      unsigned long long m = __ballot(hasp);
      bool rowHas = ((m >> ((lane >> 4) * 16)) & 0xFFFFull) != 0;
      if ((lane & 15) == 0) {
        if (v != 0.f) atomicAdd(&lossG[i], v);
        if (rowHas) atomicOr(&hasG[i], 1);
      }
    }
  }
}

// ---------------- final scalar reduce ---------------------------------------
__global__ __launch_bounds__(256) void finalize_kernel(
    const float* __restrict__ lossG, const int* __restrict__ hasG,
    float* __restrict__ out) {
  int tid = threadIdx.x;
  float s = 0.f;
  for (int i = tid; i < N; i += 256)
    if (hasG[i]) s += lossG[i];
#pragma unroll
  for (int off = 32; off >= 1; off >>= 1) s += __shfl_xor(s, off, 64);
  __shared__ float w4[4];
  if ((tid & 63) == 0) w4[tid >> 6] = s;
  __syncthreads();
  if (tid == 0) out[0] = (w4[0] + w4[1] + w4[2] + w4[3]) / (float)N;
}

extern "C" void kernel_launch(void* const* d_in, const int* in_sizes, int n_in,
                              void* d_out, int out_size, void* d_ws, size_t ws_size,
                              hipStream_t stream) {
  const float* in_col = (const float*)d_in[0];
  const int* tcol = (const int*)d_in[1];
  const float* in_row = (const float*)d_in[2];
  const int* trow = (const int*)d_in[3];
  float* out = (float*)d_out;

  char* ws = (char*)d_ws;
  float* lossG = (float*)ws;               // N floats
  int* hasG = (int*)(ws + (size_t)N * 4);  // N ints
  unsigned short* colN = (unsigned short*)(ws + (size_t)N * 8);
  unsigned short* rowN = colN + (size_t)N * D;

  hipMemsetAsync(ws, 0, (size_t)N * 8, stream);
  normalize_kernel<<<(2 * N) / 4, 256, 0, stream>>>(in_col, in_row, colN, rowN);
  loss_kernel<<<1024, 512, 0, stream>>>(colN, rowN, tcol, trow, lossG, hasG);
  finalize_kernel<<<1, 256, 0, stream>>>(lossG, hasG, out);
}

// Round 7
// 288.671 us; speedup vs baseline: 1.0191x; 1.0191x over previous
//
#include <hip/hip_runtime.h>

// ContrastiveLoss: normalize -> bf16 MFMA GEMM (A @ B^T) 256x128 tile,
// BK=32, 2 blocks/CU (m97-style multi-block overlap), fused mask/row-reduce
// epilogue -> final scalar reduce.  N=8192, D=1024. Output: f32 scalar.

constexpr int N = 8192;
constexpr int D = 1024;
constexpr int NT = D / 32;  // 32 K-tiles of BK=32

typedef short bf16x8 __attribute__((ext_vector_type(8)));
typedef float f32x4 __attribute__((ext_vector_type(4)));

static __device__ inline unsigned short f2bf(float f) {
  unsigned int u = __float_as_uint(f);
  unsigned int r = (u + 0x7fffu + ((u >> 16) & 1u)) >> 16;
  return (unsigned short)r;
}

// ---------------- normalize (+ zero the accumulators) -----------------------
__global__ __launch_bounds__(256) void normalize_kernel(
    const float* __restrict__ in_col, const float* __restrict__ in_row,
    unsigned short* __restrict__ out_col, unsigned short* __restrict__ out_row,
    unsigned int* __restrict__ zeroBase) {
  // fold the 96 KB lossG/hasG zeroing into the first 96 blocks
  if (blockIdx.x < 96) zeroBase[blockIdx.x * 256 + threadIdx.x] = 0u;

  int r = blockIdx.x * 4 + (threadIdx.x >> 6);
  int lane = threadIdx.x & 63;
  const float* in =
      (r < N) ? in_col + (size_t)r * D : in_row + (size_t)(r - N) * D;
  unsigned short* out =
      (r < N) ? out_col + (size_t)r * D : out_row + (size_t)(r - N) * D;
  float4 v[4];
  float s = 0.f;
#pragma unroll
  for (int c = 0; c < 4; c++) {
    v[c] = ((const float4*)in)[lane + c * 64];
    s += v[c].x * v[c].x + v[c].y * v[c].y + v[c].z * v[c].z + v[c].w * v[c].w;
  }
#pragma unroll
  for (int off = 32; off >= 1; off >>= 1) s += __shfl_xor(s, off, 64);
  float inv = 1.0f / sqrtf(s + 1e-12f);
#pragma unroll
  for (int c = 0; c < 4; c++) {
    ushort4 o;
    o.x = f2bf(v[c].x * inv);
    o.y = f2bf(v[c].y * inv);
    o.z = f2bf(v[c].z * inv);
    o.w = f2bf(v[c].w * inv);
    ((ushort4*)out)[lane + c * 64] = o;
  }
}

// ---------------- fused GEMM + loss epilogue --------------------------------
// 256 thr = 4 waves (2 wave-rows x 2 wave-cols). Tile 256x128, BK=32.
// LDS 48 KB: A dbuf 2x16 KB [256r][32k], B dbuf 2x8 KB [128r][32k].
// Swizzle: 16B-chunk index c ^= (row>>1)&3 (involutive; applied on stage
// source and frag read; <=2-way bank aliasing on ds_read_b128 = free).
// One __syncthreads per K-tile; 2 blocks/CU hide each other's drains.
__global__ __launch_bounds__(256, 2) void loss_kernel(
    const unsigned short* __restrict__ An, const unsigned short* __restrict__ Bn,
    const int* __restrict__ tc, const int* __restrict__ tr,
    float* __restrict__ lossG, int* __restrict__ hasG) {
  __shared__ unsigned short lds[24576];  // bytes: A [0,32768), B [32768,49152)
  char* ldsb = (char*)lds;
  const char* ldsc = (const char*)lds;

  const int tid = threadIdx.x;
  const int lane = tid & 63;
  const int wid = tid >> 6;
  const int wr = wid >> 1;  // 0..1 -> owns 128 rows
  const int wc = wid & 1;   // 0..1 -> owns 64 cols

  // XCD-aware mapping: 2048 = 8 XCD x (32 i x 8 j). Per-XCD B-panel
  // (8 j-tiles = 2 MB) stays L2-pinned; concurrent window ~8i x 8j.
  const int bid = blockIdx.x;
  const int xcd = bid & 7, s = bid >> 3;
  const int iBase = (s >> 3) * 256;
  const int jBase = (xcd * 8 + (s & 7)) * 128;

  // fragment read addressing
  const int frow = lane & 15;
  const int kx = ((lane >> 4) * 16) ^ ((lane & 6) << 3);  // swizzled k-bytes
  int rowA[8], rowB[4];
#pragma unroll
  for (int m = 0; m < 8; m++) rowA[m] = (wr * 128 + m * 16 + frow) * 64;
#pragma unroll
  for (int n = 0; n < 4; n++) rowB[n] = 32768 + (wc * 64 + n * 16 + frow) * 64;

  // staging addressing: thread t -> row (t>>2)+64p, 16B-chunk t&3
  const int srow = tid >> 2;  // 0..63
  const int c16 = tid & 3;
  const int kswz = (c16 ^ ((srow >> 1) & 3)) * 8;  // swizzled source k (elems)
  const unsigned short* aS[4];
  const unsigned short* bS[2];
#pragma unroll
  for (int p = 0; p < 4; p++)
    aS[p] = An + (size_t)(iBase + srow + 64 * p) * D + kswz;
#pragma unroll
  for (int p = 0; p < 2; p++)
    bS[p] = Bn + (size_t)(jBase + srow + 64 * p) * D + kswz;

#define GLDS(g, l)                                                        \
  __builtin_amdgcn_global_load_lds(                                       \
      (const __attribute__((address_space(1))) void*)(g),                 \
      (__attribute__((address_space(3))) void*)(l), 16, 0, 0)

  // stage K-tile tt (wrapped) into dbuf parity P: 4 A-quarters + 2 B-halves
#define STAGE(tt, P)                                                          \
  do {                                                                        \
    const int _ko = ((tt) & 31) * 32;                                         \
    _Pragma("unroll") for (int p = 0; p < 4; p++)                             \
        GLDS(aS[p] + _ko, ldsb + (P)*16384 + p * 4096 + wid * 1024);          \
    _Pragma("unroll") for (int p = 0; p < 2; p++)                             \
        GLDS(bS[p] + _ko, ldsb + 32768 + (P)*8192 + p * 4096 + wid * 1024);   \
  } while (0)

  f32x4 acc[8][4];
#pragma unroll
  for (int mi = 0; mi < 8; mi++)
#pragma unroll
    for (int ni = 0; ni < 4; ni++) acc[mi][ni] = (f32x4){0.f, 0.f, 0.f, 0.f};

  bf16x8 af[8], bf[4];

  // prologue
  STAGE(0, 0);
  __syncthreads();

#define TILE(T, P)                                                            \
  do {                                                                        \
    STAGE((T) + 1, 1 - (P));                                                  \
    _Pragma("unroll") for (int m = 0; m < 8; m++)                             \
        af[m] = *(const bf16x8*)(ldsc + (P)*16384 + rowA[m] + kx);            \
    _Pragma("unroll") for (int n = 0; n < 4; n++)                             \
        bf[n] = *(const bf16x8*)(ldsc + (P)*8192 + rowB[n] + kx);             \
    _Pragma("unroll") for (int m = 0; m < 8; m++)                             \
        _Pragma("unroll") for (int n = 0; n < 4; n++)                         \
            acc[m][n] = __builtin_amdgcn_mfma_f32_16x16x32_bf16(              \
                af[m], bf[n], acc[m][n], 0, 0, 0);                            \
    __syncthreads();                                                          \
  } while (0)

  for (int t2 = 0; t2 < NT / 2; ++t2) {
    const int t0 = 2 * t2;
    TILE(t0, 0);
    TILE(t0 + 1, 1);
  }
#undef TILE
#undef STAGE
#undef GLDS

  // ---- epilogue: mask + per-row reduce + sparse atomics ----
  // C/D layout: col = lane&15, row = (lane>>4)*4 + reg
  int trj[4];
#pragma unroll
  for (int ni = 0; ni < 4; ni++) trj[ni] = tr[jBase + wc * 64 + ni * 16 + frow];

#pragma unroll
  for (int mi = 0; mi < 8; mi++) {
#pragma unroll
    for (int r = 0; r < 4; r++) {
      const int i = iBase + wr * 128 + mi * 16 + (lane >> 4) * 4 + r;
      const int tci = tc[i];
      float v = 0.f;
      bool hasp = false;
#pragma unroll
      for (int ni = 0; ni < 4; ni++) {
        float s2 = acc[mi][ni][r];
        if (tci == trj[ni]) {
          if (s2 < 1.0f - 1e-5f) { v += 1.0f - s2; hasp = true; }
        } else if (s2 > 0.5f) {
          v += s2;
        }
      }
#pragma unroll
      for (int off = 1; off < 16; off <<= 1) v += __shfl_xor(v, off, 16);
      unsigned long long m = __ballot(hasp);
      bool rowHas = ((m >> ((lane >> 4) * 16)) & 0xFFFFull) != 0;
      if ((lane & 15) == 0) {
        if (v != 0.f) atomicAdd(&lossG[i], v);
        if (rowHas) atomicOr(&hasG[i], 1);
      }
    }
  }
}

// ---------------- final scalar reduce ---------------------------------------
__global__ __launch_bounds__(1024) void finalize_kernel(
    const float* __restrict__ lossG, const int* __restrict__ hasG,
    float* __restrict__ out) {
  int tid = threadIdx.x;
  float s = 0.f;
  for (int i = tid; i < N; i += 1024)
    if (hasG[i]) s += lossG[i];
#pragma unroll
  for (int off = 32; off >= 1; off >>= 1) s += __shfl_xor(s, off, 64);
  __shared__ float w16[16];
  if ((tid & 63) == 0) w16[tid >> 6] = s;
  __syncthreads();
  if (tid == 0) {
    float t = 0.f;
#pragma unroll
    for (int w = 0; w < 16; w++) t += w16[w];
    out[0] = t / (float)N;
  }
}

extern "C" void kernel_launch(void* const* d_in, const int* in_sizes, int n_in,
                              void* d_out, int out_size, void* d_ws, size_t ws_size,
                              hipStream_t stream) {
  const float* in_col = (const float*)d_in[0];
  const int* tcol = (const int*)d_in[1];
  const float* in_row = (const float*)d_in[2];
  const int* trow = (const int*)d_in[3];
  float* out = (float*)d_out;

  char* ws = (char*)d_ws;
  float* lossG = (float*)ws;               // N floats
  int* hasG = (int*)(ws + (size_t)N * 4);  // N ints
  unsigned short* colN = (unsigned short*)(ws + (size_t)N * 8);
  unsigned short* rowN = colN + (size_t)N * D;

  normalize_kernel<<<(2 * N) / 4, 256, 0, stream>>>(in_col, in_row, colN, rowN,
                                                    (unsigned int*)ws);
  loss_kernel<<<2048, 256, 0, stream>>>(colN, rowN, tcol, trow, lossG, hasG);
  finalize_kernel<<<1, 1024, 0, stream>>>(lossG, hasG, out);
}